// Round 3
// baseline (72.288 us; speedup 1.0000x reference)
//
#include <hip/hip_runtime.h>

#define N_AGENTS 8192
#define BLOCK    256
#define AGB      16                    // agents per block
#define PAIRS    8                     // agent-pairs per block (2 agents/thread)
#define CH       32                    // goal chunks per agent
#define GPC      (N_AGENTS / CH)       // 256 goals per chunk

// Padded LDS layout: goal g's (x,y) at float index 2*g + 4*(g>>8).
// 16B pad per 256-goal chunk => chunk bases differ by 2064B = bank offset 4,
// so the 8 distinct chunk-addresses within a wave hit disjoint banks.
__device__ __forceinline__ int gidx(int g) { return 2 * g + ((g >> 8) << 2); }

__global__ __launch_bounds__(BLOCK, 2)
void rollout_policy_kernel(const float* __restrict__ X,
                           const float* __restrict__ U,
                           int* __restrict__ out)
{
    __shared__ __align__(16) float gBuf[2 * N_AGENTS + 4 * CH];  // 66048 B
    __shared__ float sB[2][CH][PAIRS];
    __shared__ int   sI[2][CH][PAIRS];

    const int tid   = threadIdx.x;
    const int b     = blockIdx.x;
    const int slot  = tid & (PAIRS - 1);   // agent-pair slot 0..7
    const int chunk = tid >> 3;            // goal chunk 0..31

    // ---- stage all 8192 goals into padded LDS (goal rows start at 8192) ----
    const float* gp = X + 3 * N_AGENTS;
    #pragma unroll
    for (int g = tid; g < N_AGENTS; g += BLOCK) {
        int p = gidx(g);
        gBuf[p]     = gp[3 * g];
        gBuf[p + 1] = gp[3 * g + 1];
    }

    const int a0 = b * AGB + slot * 2;     // this thread's two agents: a0, a0+1
    const float ax0 = X[3 * a0],     ay0 = X[3 * a0 + 1];
    const float ax1 = X[3 * a0 + 3], ay1 = X[3 * a0 + 4];
    __syncthreads();

    // ---- argmin over this thread's 256-goal chunk for both agents ----
    float best0 = 1e30f, best1 = 1e30f;
    int   bi0 = 0, bi1 = 0;
    const int g0 = chunk * GPC;
    const float* base = &gBuf[gidx(g0)];   // 16B-aligned (2048*chunk + 16*chunk bytes)
    #pragma unroll 4
    for (int j = 0; j < GPC; j += 2) {
        float4 gg = *reinterpret_cast<const float4*>(base + 2 * j);
        float d00 = fabsf(ax0 - gg.x) + fabsf(ay0 - gg.y);
        float d01 = fabsf(ax0 - gg.z) + fabsf(ay0 - gg.w);
        float d10 = fabsf(ax1 - gg.x) + fabsf(ay1 - gg.y);
        float d11 = fabsf(ax1 - gg.z) + fabsf(ay1 - gg.w);
        // pair winner prefers lower index; then strict < vs running best
        float m0 = fminf(d00, d01); int i0 = (d01 < d00) ? (g0 + j + 1) : (g0 + j);
        float m1 = fminf(d10, d11); int i1 = (d11 < d10) ? (g0 + j + 1) : (g0 + j);
        if (m0 < best0) { best0 = m0; bi0 = i0; }
        if (m1 < best1) { best1 = m1; bi1 = i1; }
    }
    sB[0][chunk][slot] = best0;  sI[0][chunk][slot] = bi0;
    sB[1][chunk][slot] = best1;  sI[1][chunk][slot] = bi1;
    __syncthreads();

    // ---- merge 32 chunk-partials per agent (ascending chunk order keeps
    //      first-index tie-break) + fused policy tail ----
    if (tid < AGB) {
        const int half = tid & 1;          // which agent of the pair
        const int sl   = tid >> 1;         // pair slot
        float bb = sB[half][0][sl];
        int   bi = sI[half][0][sl];
        #pragma unroll
        for (int c = 1; c < CH; ++c) {
            float v = sB[half][c][sl];
            if (v < bb) { bb = v; bi = sI[half][c][sl]; }
        }
        const int a  = b * AGB + tid;
        const float ax = X[3 * a], ay = X[3 * a + 1];
        const int   p  = gidx(bi);
        const float dx = gBuf[p]     - ax;
        const float dy = gBuf[p + 1] - ay;

        float p0 = dx > 0.0f ? 1.0f : 0.0f;
        float p1 = dx < 0.0f ? 1.0f : 0.0f;
        float p2 = dy > 0.0f ? 1.0f : 0.0f;
        float p3 = dy < 0.0f ? 1.0f : 0.0f;
        float p4 = (dx == 0.0f && dy == 0.0f) ? 1.0f : 0.0f;

        float c0 = p0;
        float c1 = c0 + p1;
        float c2 = c1 + p2;
        float c3 = c2 + p3;
        float c4 = c3 + p4;

        float t = U[a] * c4;
        int action = (c0 >= t) ? 0
                   : (c1 >= t) ? 1
                   : (c2 >= t) ? 2
                   : (c3 >= t) ? 3
                   : 4;
        out[a] = action;
    }
}

extern "C" void kernel_launch(void* const* d_in, const int* in_sizes, int n_in,
                              void* d_out, int out_size, void* d_ws, size_t ws_size,
                              hipStream_t stream)
{
    const float* X = (const float*)d_in[0];   // (16384, 3) f32
    const float* U = (const float*)d_in[1];   // (8192,)    f32
    int* out = (int*)d_out;                   // (8192,)    i32

    dim3 grid(N_AGENTS / AGB);   // 512 blocks -> 2 per CU
    dim3 block(BLOCK);
    rollout_policy_kernel<<<grid, block, 0, stream>>>(X, U, out);
}

// Round 4
// 70.839 us; speedup vs baseline: 1.0205x; 1.0205x over previous
//
#include <hip/hip_runtime.h>

#define N_AGENTS 8192
#define BLOCK    256
#define AGB      16                    // agents per block
#define PAIRS    8                     // agent-pairs per block (2 agents/thread)
#define CH       32                    // goal chunks per agent
#define GPC      (N_AGENTS / CH)       // 256 goals per chunk

// Padded LDS layout: goal g's (x,y) at float index 2*g + 4*(g>>8).
// 16B pad per 256-goal chunk => the 8 distinct chunk base addresses within a
// wave land on banks 0,4,...,28 -> conflict-free broadcast reads.
__device__ __forceinline__ int gidx(int g) { return 2 * g + ((g >> 8) << 2); }

__global__ __launch_bounds__(BLOCK, 2)
void rollout_policy_kernel(const float* __restrict__ X,
                           const float* __restrict__ U,
                           int* __restrict__ out)
{
    __shared__ __align__(16) float gBuf[2 * N_AGENTS + 4 * CH];  // 66048 B
    __shared__ float sB[2][CH][PAIRS];
    __shared__ int   sI[2][CH][PAIRS];

    const int tid   = threadIdx.x;
    const int b     = blockIdx.x;
    const int slot  = tid & (PAIRS - 1);   // agent-pair slot 0..7
    const int chunk = tid >> 3;            // goal chunk 0..31

    // ---- stage all 8192 goals into padded LDS, fully vectorized ----
    // 4 goals = 12 floats = 3 float4 global loads -> 2 float4 LDS writes.
    // (goal rows start at float 3*N_AGENTS; that offset is 16B-aligned)
    const float4* gp4 = reinterpret_cast<const float4*>(X + 3 * N_AGENTS);
    #pragma unroll
    for (int k = tid; k < N_AGENTS / 4; k += BLOCK) {
        float4 q0 = gp4[3 * k];        // x0 y0 z0 x1
        float4 q1 = gp4[3 * k + 1];    // y1 z1 x2 y2
        float4 q2 = gp4[3 * k + 2];    // z2 x3 y3 z3
        int p = gidx(4 * k);           // 16B-aligned (8k floats + 16B pads)
        *reinterpret_cast<float4*>(&gBuf[p])     = make_float4(q0.x, q0.y, q0.w, q1.x);
        *reinterpret_cast<float4*>(&gBuf[p + 4]) = make_float4(q1.z, q1.w, q2.y, q2.z);
    }

    const int a0 = b * AGB + slot * 2;     // this thread's two agents: a0, a0+1
    const float ax0 = X[3 * a0],     ay0 = X[3 * a0 + 1];
    const float ax1 = X[3 * a0 + 3], ay1 = X[3 * a0 + 4];
    __syncthreads();

    // ---- argmin over this thread's 256-goal chunk for both agents ----
    float best0 = 1e30f, best1 = 1e30f;
    int   bi0 = 0, bi1 = 0;
    const int g0 = chunk * GPC;
    const float* base = &gBuf[gidx(g0)];
    #pragma unroll 8
    for (int j = 0; j < GPC; j += 2) {
        float4 gg = *reinterpret_cast<const float4*>(base + 2 * j);
        float d00 = fabsf(ax0 - gg.x) + fabsf(ay0 - gg.y);
        float d01 = fabsf(ax0 - gg.z) + fabsf(ay0 - gg.w);
        float d10 = fabsf(ax1 - gg.x) + fabsf(ay1 - gg.y);
        float d11 = fabsf(ax1 - gg.z) + fabsf(ay1 - gg.w);
        // pair winner prefers lower index; then strict < vs running best
        float m0 = fminf(d00, d01); int i0 = (d01 < d00) ? (g0 + j + 1) : (g0 + j);
        float m1 = fminf(d10, d11); int i1 = (d11 < d10) ? (g0 + j + 1) : (g0 + j);
        if (m0 < best0) { best0 = m0; bi0 = i0; }
        if (m1 < best1) { best1 = m1; bi1 = i1; }
    }
    sB[0][chunk][slot] = best0;  sI[0][chunk][slot] = bi0;
    sB[1][chunk][slot] = best1;  sI[1][chunk][slot] = bi1;
    __syncthreads();

    // ---- merge 32 chunk-partials per agent (ascending chunk order keeps
    //      first-index tie-break = jnp.argmin semantics) + fused policy tail ----
    if (tid < AGB) {
        const int half = tid & 1;          // which agent of the pair
        const int sl   = tid >> 1;         // pair slot
        float bb = sB[half][0][sl];
        int   bi = sI[half][0][sl];
        #pragma unroll
        for (int c = 1; c < CH; ++c) {
            float v = sB[half][c][sl];
            if (v < bb) { bb = v; bi = sI[half][c][sl]; }
        }
        const int a  = b * AGB + tid;
        const float ax = X[3 * a], ay = X[3 * a + 1];
        const int   p  = gidx(bi);
        const float dx = gBuf[p]     - ax;
        const float dy = gBuf[p + 1] - ay;

        float p0 = dx > 0.0f ? 1.0f : 0.0f;
        float p1 = dx < 0.0f ? 1.0f : 0.0f;
        float p2 = dy > 0.0f ? 1.0f : 0.0f;
        float p3 = dy < 0.0f ? 1.0f : 0.0f;
        float p4 = (dx == 0.0f && dy == 0.0f) ? 1.0f : 0.0f;

        float c0 = p0;
        float c1 = c0 + p1;
        float c2 = c1 + p2;
        float c3 = c2 + p3;
        float c4 = c3 + p4;

        float t = U[a] * c4;
        int action = (c0 >= t) ? 0
                   : (c1 >= t) ? 1
                   : (c2 >= t) ? 2
                   : (c3 >= t) ? 3
                   : 4;
        out[a] = action;
    }
}

extern "C" void kernel_launch(void* const* d_in, const int* in_sizes, int n_in,
                              void* d_out, int out_size, void* d_ws, size_t ws_size,
                              hipStream_t stream)
{
    const float* X = (const float*)d_in[0];   // (16384, 3) f32
    const float* U = (const float*)d_in[1];   // (8192,)    f32
    int* out = (int*)d_out;                   // (8192,)    i32

    dim3 grid(N_AGENTS / AGB);   // 512 blocks -> 2 per CU
    dim3 block(BLOCK);
    rollout_policy_kernel<<<grid, block, 0, stream>>>(X, U, out);
}